// Round 7
// baseline (334.556 us; speedup 1.0000x reference)
//
#include <hip/hip_runtime.h>
#include <hip/hip_bf16.h>
#include <cstdint>

// ---------------------------------------------------------------------------
// WindowAttention, fully fused: B windows (2048), N=64, DIM=192, H=6, d=32.
//   prep : weights -> bf16 MFMA-fragment-linear, comb = rel_bias+mask (bf16,
//          packed [w][h][rowblk][col][4rows] so a lane's 4-row slice = one 8B load)
//   fused: per-window block (512 thr, 8 waves). 3 passes over head-pairs:
//            QKV GEMM (A-frags in regs, B-frags 2-deep from L2)
//            -> Q,K,V^T in LDS -> attention (1 task/wave, softmax in regs)
//            -> Xa slice in LDS -> rank-64 proj update into reg acc.
// Round-7 analysis: VGPR_Count (84-88) EXCLUDES AGPRs; combined ~136 > 128
// cliff -> only 1 block/CU resident (occupancy 22-23% in R3/R5/R6).
// Levers: comb->bf16-packed (-8 regs), per-row softmax P-store (-12 regs),
// __launch_bounds__(512,4) = combined cap 128 -> 2 blocks/CU guaranteed.
// (R4's disaster was cap 85 vs need 136; now cap 128 vs need ~120.)
// ---------------------------------------------------------------------------

#define NTOK 64
#define NH 6
#define HD 32
#define WDIM 192
#define SCALE 0.17677669529663689f

typedef __bf16 bf16x8 __attribute__((ext_vector_type(8)));
typedef float f32x4 __attribute__((ext_vector_type(4)));

__device__ inline unsigned short f2bf(float f) {
    union { __bf16 b; unsigned short s; } u;
    u.b = (__bf16)f;                     // native RNE convert
    return u.s;
}

__device__ inline float bfbits2f(unsigned short s) {
    union { unsigned u; float f; } v; v.u = ((unsigned)s) << 16;
    return v.f;
}

// ---------------------------------------------------------------------------
// K0: weight cast into MFMA B-fragment-linear order + combined bias table.
// Wfrag[((ntile*6 + ks)*64 + lane)*8 + j] = W[k][n], n = ntile*16+(lane&15),
// k = ks*32+(lane>>4)*8+j  -> a wave's B-fragment is one coalesced 1KB read.
// comb_bf[((w*6+h)*16 + rb)*64*4 + c*4 + rr] = bf16(rpbt[relidx(rb*4+rr,c)][h]
//                                            + mask[w][rb*4+rr][c])
// so attention lane (quad,l15) loads rows {quad*4+0..3} of col j*16+l15 as
// ONE uint2 (8B). Total 64*6*16*64*4 ushorts = 3.1MB.
// ---------------------------------------------------------------------------
__global__ __launch_bounds__(256) void prep_kernel(
    const float* __restrict__ w_qkv, const float* __restrict__ w_proj,
    const float* __restrict__ rpbt, const float* __restrict__ mask,
    unsigned short* __restrict__ wqkv_f, unsigned short* __restrict__ wproj_f,
    unsigned short* __restrict__ comb_bf) {
    int idx = blockIdx.x * 256 + threadIdx.x;
    if (idx < 576 * 192) {
        int j = idx & 7, lane = (idx >> 3) & 63, t = idx >> 9;   // t = 0..215
        int ks = t % 6, ntile = t / 6;                           // ntile 0..35
        int n = ntile * 16 + (lane & 15);                        // 0..575
        int k = ks * 32 + (lane >> 4) * 8 + j;                   // 0..191
        wqkv_f[idx] = f2bf(w_qkv[k * 576 + n]);
        return;
    }
    int i2 = idx - 576 * 192;
    if (i2 < 192 * 192) {
        int j = i2 & 7, lane = (i2 >> 3) & 63, t = i2 >> 9;      // t = 0..71
        int ks = t % 6, ntile = t / 6;                           // ntile 0..11
        int n = ntile * 16 + (lane & 15);                        // 0..191
        int k = ks * 32 + (lane >> 4) * 8 + j;                   // 0..191
        wproj_f[i2] = f2bf(w_proj[k * 192 + n]);
        return;
    }
    int i3 = i2 - 192 * 192;
    if (i3 < 64 * NH * NTOK * NTOK) {
        int rr = i3 & 3;                     // row within 4-row pack
        int c = (i3 >> 2) & 63;              // col
        int rb = (i3 >> 8) & 15;             // row block
        int h = (i3 >> 12) % NH;
        int w = i3 / (NH * 4096);
        int r = rb * 4 + rr;
        int rrd = (r >> 3) - (c >> 3) + 7;    // row-coord delta (0..14)
        int ccd = (r & 7) - (c & 7) + 7;      // col-coord delta (0..14)
        comb_bf[i3] = f2bf(rpbt[(rrd * 15 + ccd) * NH + h]
                           + mask[w * 4096 + r * 64 + c]);
    }
}

// ---------------------------------------------------------------------------
// Fused per-window kernel. 512 threads = 8 waves: wm = wave>>2 (row half),
// wn = wave&3 (n-group). Static LDS: sm[28672] shorts = 57344 B.
//   phase 0 : lx  = sm[0..12800)            X bf16 [64][200]
//   overlay : lq2 = sm[0..5120)             Q pair [2][64][40]
//             lk2 = sm[5120..10240)         K pair [2][64][40]
//             lvt2= sm[10240..14848)        V^T    [2][32][72]
//             lxa = sm[14848..19456)        Xa slice [64][72]
//   separate: lsp = sm[19456 + wave*1152)   P scratch [16][72]/wave
// Barriers/pass: B1 (pre-epilogue), B2 (post-epilogue), B4 (pre-proj).
// ---------------------------------------------------------------------------
__global__ __launch_bounds__(512, 4) void fused_kernel(
    const float* __restrict__ X, const unsigned short* __restrict__ Wqf,
    const float* __restrict__ b_qkv, const unsigned short* __restrict__ Wpf,
    const float* __restrict__ b_proj, const unsigned short* __restrict__ comb_bf,
    float* __restrict__ out) {
    __shared__ unsigned short sm[28672];
    unsigned short* lx   = sm;              // [64][200], dies at af-hoist
    unsigned short* lq2  = sm;              // [2][64][40]
    unsigned short* lk2  = sm + 5120;       // [2][64][40]
    unsigned short* lvt2 = sm + 10240;      // [2][32][72]
    unsigned short* lxa  = sm + 14848;      // [64][72]

    const int tid = threadIdx.x;
    const int bwin = blockIdx.x;
    const int wave = tid >> 6, lane = tid & 63;
    const int l15 = lane & 15, quad = lane >> 4;
    const int wm = wave >> 2, wn = wave & 3;

    // ---- stage X (64x192 fp32 -> bf16) ----
    const float4* xg = (const float4*)(X + (size_t)bwin * 64 * 192);
    for (int i = 0; i < 6; i++) {
        int e4 = tid + i * 512;            // 3072 float4
        int row = e4 / 48, c4 = e4 % 48;
        float4 v = xg[e4];
        union { unsigned short s[4]; uint2 u; } pk;
        pk.s[0] = f2bf(v.x); pk.s[1] = f2bf(v.y);
        pk.s[2] = f2bf(v.z); pk.s[3] = f2bf(v.w);
        *(uint2*)&lx[row * 200 + c4 * 4] = pk.u;
    }
    __syncthreads();

    // ---- hoist A-fragments (X rows wm*32..+32, all K) into registers ----
    bf16x8 af[2][6];
    for (int mt = 0; mt < 2; mt++)
        for (int ks = 0; ks < 6; ks++)
            af[mt][ks] = *(const bf16x8*)&lx[(wm * 32 + mt * 16 + l15) * 200 + ks * 32 + quad * 8];
    // lx dead from here (overlay becomes writable after B1 of pass 0)
    unsigned short* lspw = sm + 19456 + wave * 1152;   // [16][72] per wave

    f32x4 pacc[2][3];                           // proj accumulator, all passes
    for (int mt = 0; mt < 2; mt++)
        for (int nt = 0; nt < 3; nt++)
            pacc[mt][nt] = (f32x4){0.f, 0.f, 0.f, 0.f};

    // per-(bwin&63) comb base, packed bf16 layout: [w][h][rb][c][rr]
    const unsigned short* combg = comb_bf + ((size_t)(bwin & 63) * NH) * 4096;

    for (int p = 0; p < 3; p++) {
        const int hl = wm;                 // this wave's attn head (local)
        const int mbase = wn * 16;         // this wave's attn query tile
        const int hg = p * 2 + hl;         // global head

        // issue packed comb loads now (4 x 8B): hidden under the QKV GEMM
        uint2 cmbp[4];
        #pragma unroll
        for (int j = 0; j < 4; j++)
            cmbp[j] = *(const uint2*)&combg[
                (((size_t)hg * 16 + (mbase >> 2) + quad) * 64 + j * 16 + l15) * 4];

        // ---- QKV GEMM for head-pair p, B-frags 2-deep pipelined ----
        const unsigned short* wptr[3];
        #pragma unroll
        for (int i = 0; i < 3; i++) {
            int f = wn * 3 + i, c = f >> 2, j = f & 3;
            wptr[i] = Wqf + ((size_t)((c * 12 + p * 4 + j) * 6)) * 512 + lane * 8;
        }
        f32x4 acc[2][3];
        #pragma unroll
        for (int mt = 0; mt < 2; mt++)
            #pragma unroll
            for (int i = 0; i < 3; i++)
                acc[mt][i] = (f32x4){0.f, 0.f, 0.f, 0.f};

        bf16x8 bcur[3], bnxt[3];
        #pragma unroll
        for (int i = 0; i < 3; i++)
            bcur[i] = *(const bf16x8*)(wptr[i]);
        #pragma unroll
        for (int ks = 0; ks < 6; ks++) {
            if (ks < 5) {
                #pragma unroll
                for (int i = 0; i < 3; i++)
                    bnxt[i] = *(const bf16x8*)(wptr[i] + (ks + 1) * 512);
            }
            #pragma unroll
            for (int mt = 0; mt < 2; mt++)
                #pragma unroll
                for (int i = 0; i < 3; i++)
                    acc[mt][i] = __builtin_amdgcn_mfma_f32_16x16x32_bf16(
                        af[mt][ks], bcur[i], acc[mt][i], 0, 0, 0);
            #pragma unroll
            for (int i = 0; i < 3; i++)
                bcur[i] = bnxt[i];
        }
        // B1: prev pass's attention/proj LDS reads done (p=0: af-hoist done)
        __syncthreads();
        // epilogue -> LDS. C/D layout: col = l15, row = quad*4 + r
        #pragma unroll
        for (int i = 0; i < 3; i++) {
            int f = wn * 3 + i, c = f >> 2, j = f & 3;
            int cw = j * 16 + l15;                 // 0..63 within pass
            float bias = b_qkv[c * 192 + p * 64 + cw];
            int hle = cw >> 5, d = cw & 31;
            if (c < 2) {
                unsigned short* dst = (c == 0) ? lq2 : lk2;
                #pragma unroll
                for (int mt = 0; mt < 2; mt++)
                    #pragma unroll
                    for (int r = 0; r < 4; r++) {
                        int t = wm * 32 + mt * 16 + quad * 4 + r;
                        dst[(hle * 64 + t) * 40 + d] = f2bf(acc[mt][i][r] + bias);
                    }
            } else {
                #pragma unroll
                for (int mt = 0; mt < 2; mt++) {
                    union { unsigned short s[4]; uint2 u; } pk;
                    #pragma unroll
                    for (int r = 0; r < 4; r++)
                        pk.s[r] = f2bf(acc[mt][i][r] + bias);
                    int t0 = wm * 32 + mt * 16 + quad * 4;
                    *(uint2*)&lvt2[(hle * 32 + d) * 72 + t0] = pk.u;
                }
            }
        }
        __syncthreads();   // B2: Q/K/V^T visible to all waves

        // ---- attention: 8 tasks, exactly one per wave ----
        // S = Q K^T (d=32 = one k-step)
        bf16x8 aq = *(const bf16x8*)&lq2[(hl * 64 + mbase + l15) * 40 + quad * 8];
        f32x4 sacc[4];
        #pragma unroll
        for (int j = 0; j < 4; j++) {
            bf16x8 bk = *(const bf16x8*)&lk2[(hl * 64 + j * 16 + l15) * 40 + quad * 8];
            f32x4 z = (f32x4){0.f, 0.f, 0.f, 0.f};
            sacc[j] = __builtin_amdgcn_mfma_f32_16x16x32_bf16(aq, bk, z, 0, 0, 0);
        }

        // softmax, per-row (pr transient, P stored unnormalized immediately)
        float rsum[4];
        #pragma unroll
        for (int r = 0; r < 4; r++) {
            float s0 = sacc[0][r] * SCALE + bfbits2f(((const unsigned short*)&cmbp[0])[r]);
            float s1 = sacc[1][r] * SCALE + bfbits2f(((const unsigned short*)&cmbp[1])[r]);
            float s2 = sacc[2][r] * SCALE + bfbits2f(((const unsigned short*)&cmbp[2])[r]);
            float s3 = sacc[3][r] * SCALE + bfbits2f(((const unsigned short*)&cmbp[3])[r]);
            float m = fmaxf(fmaxf(s0, s1), fmaxf(s2, s3));
            for (int o = 1; o < 16; o <<= 1) m = fmaxf(m, __shfl_xor(m, o, 64));
            float p0 = __expf(s0 - m), p1 = __expf(s1 - m);
            float p2 = __expf(s2 - m), p3 = __expf(s3 - m);
            float su = p0 + p1 + p2 + p3;
            for (int o = 1; o < 16; o <<= 1) su += __shfl_xor(su, o, 64);
            rsum[r] = su;
            int row = quad * 4 + r;
            lspw[row * 72 +  0 + l15] = f2bf(p0);
            lspw[row * 72 + 16 + l15] = f2bf(p1);
            lspw[row * 72 + 32 + l15] = f2bf(p2);
            lspw[row * 72 + 48 + l15] = f2bf(p3);
        }

        // O = P V^T  (K=64 -> 2 k-steps, 2 d-tiles); same-wave RAW on lspw
        f32x4 oacc[2];
        oacc[0] = (f32x4){0.f, 0.f, 0.f, 0.f};
        oacc[1] = (f32x4){0.f, 0.f, 0.f, 0.f};
        #pragma unroll
        for (int kstep = 0; kstep < 2; kstep++) {
            bf16x8 ap = *(const bf16x8*)&lspw[l15 * 72 + kstep * 32 + quad * 8];
            #pragma unroll
            for (int n2 = 0; n2 < 2; n2++) {
                bf16x8 bv = *(const bf16x8*)&lvt2[
                    (hl * 32 + n2 * 16 + l15) * 72 + kstep * 32 + quad * 8];
                oacc[n2] = __builtin_amdgcn_mfma_f32_16x16x32_bf16(ap, bv, oacc[n2], 0, 0, 0);
            }
        }

        // prefetch proj B-frags kk=0 (hide L2 latency under normalize + B4)
        bf16x8 pb0[3];
        #pragma unroll
        for (int nt = 0; nt < 3; nt++)
            pb0[nt] = *(const bf16x8*)&Wpf[
                ((size_t)((wn * 3 + nt) * 6 + (p * 2 + 0))) * 512 + lane * 8];

        // normalize + write Xa slice (bf16): col = hl*32 + d
        #pragma unroll
        for (int r = 0; r < 4; r++) {
            float inv = 1.0f / rsum[r];
            int t = mbase + quad * 4 + r;
            #pragma unroll
            for (int n2 = 0; n2 < 2; n2++)
                lxa[t * 72 + hl * 32 + n2 * 16 + l15] = f2bf(oacc[n2][r] * inv);
        }
        __syncthreads();   // B4: lxa visible cross-wave

        // ---- proj partial: rank-64 update, k-slice [p*64, p*64+64) ----
        bf16x8 pb1[3];
        #pragma unroll
        for (int nt = 0; nt < 3; nt++)
            pb1[nt] = *(const bf16x8*)&Wpf[
                ((size_t)((wn * 3 + nt) * 6 + (p * 2 + 1))) * 512 + lane * 8];
        bf16x8 pf[2][2];
        #pragma unroll
        for (int mt = 0; mt < 2; mt++)
            #pragma unroll
            for (int kk = 0; kk < 2; kk++)
                pf[mt][kk] = *(const bf16x8*)&lxa[
                    (wm * 32 + mt * 16 + l15) * 72 + kk * 32 + quad * 8];
        #pragma unroll
        for (int mt = 0; mt < 2; mt++)
            #pragma unroll
            for (int nt = 0; nt < 3; nt++)
                pacc[mt][nt] = __builtin_amdgcn_mfma_f32_16x16x32_bf16(
                    pf[mt][0], pb0[nt], pacc[mt][nt], 0, 0, 0);
        #pragma unroll
        for (int mt = 0; mt < 2; mt++)
            #pragma unroll
            for (int nt = 0; nt < 3; nt++)
                pacc[mt][nt] = __builtin_amdgcn_mfma_f32_16x16x32_bf16(
                    pf[mt][1], pb1[nt], pacc[mt][nt], 0, 0, 0);
        // next pass's B1 protects lq2/lk2/lvt2/lxa reuse
    }

    // ---- write out (fp32 + bias) ----
    for (int nt = 0; nt < 3; nt++) {
        int cw = wn * 48 + nt * 16 + l15;       // 0..191
        float bias = b_proj[cw];
        for (int mt = 0; mt < 2; mt++)
            for (int r = 0; r < 4; r++) {
                int t = wm * 32 + mt * 16 + quad * 4 + r;
                out[((size_t)bwin * 64 + t) * 192 + cw] = pacc[mt][nt][r] + bias;
            }
    }
}

// ---------------------------------------------------------------------------
extern "C" void kernel_launch(void* const* d_in, const int* in_sizes, int n_in,
                              void* d_out, int out_size, void* d_ws, size_t ws_size,
                              hipStream_t stream) {
    const float* x      = (const float*)d_in[0];
    const float* mask   = (const float*)d_in[1];
    const float* w_qkv  = (const float*)d_in[2];
    const float* b_qkv  = (const float*)d_in[3];
    const float* rpbt   = (const float*)d_in[4];
    const float* w_proj = (const float*)d_in[5];
    const float* b_proj = (const float*)d_in[6];
    float* out = (float*)d_out;

    const int B = in_sizes[0] / (NTOK * WDIM);   // 2048

    char* ws = (char*)d_ws;
    size_t o = 0;
    unsigned short* Wq = (unsigned short*)(ws + o); o += 576 * 192 * 2;
    unsigned short* Wp = (unsigned short*)(ws + o); o += 192 * 192 * 2;
    unsigned short* comb_bf = (unsigned short*)(ws + o);
    o += (size_t)64 * NH * NTOK * NTOK * 2;

    const int prep_elems = 576 * 192 + 192 * 192 + 64 * NH * NTOK * NTOK;
    prep_kernel<<<(prep_elems + 255) / 256, 256, 0, stream>>>(
        w_qkv, w_proj, rpbt, mask, Wq, Wp, comb_bf);
    fused_kernel<<<B, 512, 0, stream>>>(
        x, Wq, b_qkv, Wp, b_proj, comb_bf, out);
}

// Round 8
// 261.073 us; speedup vs baseline: 1.2815x; 1.2815x over previous
//
#include <hip/hip_runtime.h>
#include <hip/hip_bf16.h>
#include <cstdint>

// ---------------------------------------------------------------------------
// WindowAttention, fully fused: B windows (2048), N=64, DIM=192, H=6, d=32.
//   prep : weights -> bf16 MFMA-fragment-linear; comb = rel_bias+mask packed
//          bf16 [w][h][rowblk][col][4rows] (lane's 4-row slice = one 8B load)
//   fused: per-window block (512 thr, 8 waves). 3 passes over head-pairs:
//            QKV GEMM (A-frags streamed from persistent LDS X, B-frags 2-deep
//            from L2) -> Q,K,V^T in LDS -> attention (1 task/wave, softmax in
//            regs) -> Xa slice in LDS -> rank-64 proj update into reg acc.
// Register history: R3/R5/R6 combined VGPR+AGPR ~136 > 128 -> 1 block/CU
// (occupancy 22%); R7 capped at 128 with need 136 -> spill (FETCH/WRITE
// +210MB each, 208us). This round cuts NEED: af[2][6] hoist (48 regs held
// kernel-wide) replaced by per-k-step LDS streaming from a persistent lx
// (<=32 transient). Peak need ~116 < cap 128 -> 2 blocks/CU, no spill.
// ---------------------------------------------------------------------------

#define NTOK 64
#define NH 6
#define HD 32
#define WDIM 192
#define SCALE 0.17677669529663689f

typedef __bf16 bf16x8 __attribute__((ext_vector_type(8)));
typedef float f32x4 __attribute__((ext_vector_type(4)));

__device__ inline unsigned short f2bf(float f) {
    union { __bf16 b; unsigned short s; } u;
    u.b = (__bf16)f;                     // native RNE convert
    return u.s;
}

__device__ inline float bfbits2f(unsigned short s) {
    union { unsigned u; float f; } v; v.u = ((unsigned)s) << 16;
    return v.f;
}

// ---------------------------------------------------------------------------
// K0: weight cast into MFMA B-fragment-linear order + combined bias table.
// Wfrag[((ntile*6 + ks)*64 + lane)*8 + j] = W[k][n], n = ntile*16+(lane&15),
// k = ks*32+(lane>>4)*8+j  -> a wave's B-fragment is one coalesced 1KB read.
// comb_bf[((w*6+h)*16 + rb)*64*4 + c*4 + rr] = bf16(rpbt[relidx(rb*4+rr,c)][h]
//                                            + mask[w][rb*4+rr][c])
// ---------------------------------------------------------------------------
__global__ __launch_bounds__(256) void prep_kernel(
    const float* __restrict__ w_qkv, const float* __restrict__ w_proj,
    const float* __restrict__ rpbt, const float* __restrict__ mask,
    unsigned short* __restrict__ wqkv_f, unsigned short* __restrict__ wproj_f,
    unsigned short* __restrict__ comb_bf) {
    int idx = blockIdx.x * 256 + threadIdx.x;
    if (idx < 576 * 192) {
        int j = idx & 7, lane = (idx >> 3) & 63, t = idx >> 9;   // t = 0..215
        int ks = t % 6, ntile = t / 6;                           // ntile 0..35
        int n = ntile * 16 + (lane & 15);                        // 0..575
        int k = ks * 32 + (lane >> 4) * 8 + j;                   // 0..191
        wqkv_f[idx] = f2bf(w_qkv[k * 576 + n]);
        return;
    }
    int i2 = idx - 576 * 192;
    if (i2 < 192 * 192) {
        int j = i2 & 7, lane = (i2 >> 3) & 63, t = i2 >> 9;      // t = 0..71
        int ks = t % 6, ntile = t / 6;                           // ntile 0..11
        int n = ntile * 16 + (lane & 15);                        // 0..191
        int k = ks * 32 + (lane >> 4) * 8 + j;                   // 0..191
        wproj_f[i2] = f2bf(w_proj[k * 192 + n]);
        return;
    }
    int i3 = i2 - 192 * 192;
    if (i3 < 64 * NH * NTOK * NTOK) {
        int rr = i3 & 3;                     // row within 4-row pack
        int c = (i3 >> 2) & 63;              // col
        int rb = (i3 >> 8) & 15;             // row block
        int h = (i3 >> 12) % NH;
        int w = i3 / (NH * 4096);
        int r = rb * 4 + rr;
        int rrd = (r >> 3) - (c >> 3) + 7;    // row-coord delta (0..14)
        int ccd = (r & 7) - (c & 7) + 7;      // col-coord delta (0..14)
        comb_bf[i3] = f2bf(rpbt[(rrd * 15 + ccd) * NH + h]
                           + mask[w * 4096 + r * 64 + c]);
    }
}

// ---------------------------------------------------------------------------
// Fused per-window kernel. 512 threads = 8 waves: wm = wave>>2 (row half),
// wn = wave&3 (n-group). Static LDS: sm[32256] shorts = 64512 B (64KB limit).
//   lx  : sm[0..12800)        X bf16 [64][200]  PERSISTENT (all passes)
//   lq2 : sm[12800..17920)    Q pair [2][64][40]
//   lk2 : sm[17920..23040)    K pair [2][64][40]
//   lvt2: sm[23040..27648)    V^T    [2][32][72]
//   lxa : sm[27648..32256)    Xa slice [64][72]
//   lsp : sm[12800 + wave*1152) P scratch [16][72]/wave, overlays lq2/lk2,
//         legalized by barrier B3 after the QK^T MFMA reads.
// Barriers/pass: B1 (pre-epilogue), B2 (post-epilogue), B3 (post-QK^T),
// B4 (pre-proj).
// ---------------------------------------------------------------------------
__global__ __launch_bounds__(512, 4) void fused_kernel(
    const float* __restrict__ X, const unsigned short* __restrict__ Wqf,
    const float* __restrict__ b_qkv, const unsigned short* __restrict__ Wpf,
    const float* __restrict__ b_proj, const unsigned short* __restrict__ comb_bf,
    float* __restrict__ out) {
    __shared__ unsigned short sm[32256];
    unsigned short* lx   = sm;              // [64][200] persistent
    unsigned short* lq2  = sm + 12800;      // [2][64][40]
    unsigned short* lk2  = sm + 17920;      // [2][64][40]
    unsigned short* lvt2 = sm + 23040;      // [2][32][72]
    unsigned short* lxa  = sm + 27648;      // [64][72]

    const int tid = threadIdx.x;
    const int bwin = blockIdx.x;
    const int wave = tid >> 6, lane = tid & 63;
    const int l15 = lane & 15, quad = lane >> 4;
    const int wm = wave >> 2, wn = wave & 3;

    unsigned short* lspw = sm + 12800 + wave * 1152;   // [16][72] per wave

    // ---- stage X (64x192 fp32 -> bf16) ----
    const float4* xg = (const float4*)(X + (size_t)bwin * 64 * 192);
    for (int i = 0; i < 6; i++) {
        int e4 = tid + i * 512;            // 3072 float4
        int row = e4 / 48, c4 = e4 % 48;
        float4 v = xg[e4];
        union { unsigned short s[4]; uint2 u; } pk;
        pk.s[0] = f2bf(v.x); pk.s[1] = f2bf(v.y);
        pk.s[2] = f2bf(v.z); pk.s[3] = f2bf(v.w);
        *(uint2*)&lx[row * 200 + c4 * 4] = pk.u;
    }
    __syncthreads();

    f32x4 pacc[2][3];                           // proj accumulator, all passes
    for (int mt = 0; mt < 2; mt++)
        for (int nt = 0; nt < 3; nt++)
            pacc[mt][nt] = (f32x4){0.f, 0.f, 0.f, 0.f};

    // per-(bwin&63) comb base, packed bf16 layout: [w][h][rb][c][rr]
    const unsigned short* combg = comb_bf + ((size_t)(bwin & 63) * NH) * 4096;

    for (int p = 0; p < 3; p++) {
        const int hl = wm;                 // this wave's attn head (local)
        const int mbase = wn * 16;         // this wave's attn query tile
        const int hg = p * 2 + hl;         // global head

        // ---- QKV GEMM for head-pair p: A from LDS (2-deep), B from L2
        // (2-deep). No kernel-wide A hoist -> peak regs ~116 < 128 cap. ----
        const unsigned short* wptr[3];
        #pragma unroll
        for (int i = 0; i < 3; i++) {
            int f = wn * 3 + i, c = f >> 2, j = f & 3;
            wptr[i] = Wqf + ((size_t)((c * 12 + p * 4 + j) * 6)) * 512 + lane * 8;
        }
        f32x4 acc[2][3];
        #pragma unroll
        for (int mt = 0; mt < 2; mt++)
            #pragma unroll
            for (int i = 0; i < 3; i++)
                acc[mt][i] = (f32x4){0.f, 0.f, 0.f, 0.f};

        bf16x8 acur[2], anxt[2], bcur[3], bnxt[3];
        #pragma unroll
        for (int mt = 0; mt < 2; mt++)
            acur[mt] = *(const bf16x8*)&lx[(wm * 32 + mt * 16 + l15) * 200 + quad * 8];
        #pragma unroll
        for (int i = 0; i < 3; i++)
            bcur[i] = *(const bf16x8*)(wptr[i]);
        #pragma unroll
        for (int ks = 0; ks < 6; ks++) {
            if (ks < 5) {
                #pragma unroll
                for (int mt = 0; mt < 2; mt++)
                    anxt[mt] = *(const bf16x8*)&lx[
                        (wm * 32 + mt * 16 + l15) * 200 + (ks + 1) * 32 + quad * 8];
                #pragma unroll
                for (int i = 0; i < 3; i++)
                    bnxt[i] = *(const bf16x8*)(wptr[i] + (ks + 1) * 512);
            }
            #pragma unroll
            for (int mt = 0; mt < 2; mt++)
                #pragma unroll
                for (int i = 0; i < 3; i++)
                    acc[mt][i] = __builtin_amdgcn_mfma_f32_16x16x32_bf16(
                        acur[mt], bcur[i], acc[mt][i], 0, 0, 0);
            #pragma unroll
            for (int mt = 0; mt < 2; mt++) acur[mt] = anxt[mt];
            #pragma unroll
            for (int i = 0; i < 3; i++) bcur[i] = bnxt[i];
        }

        // issue packed comb loads now (4 x 8B): latency hides under the
        // epilogue + B2 barrier + QK^T; regs not live during the GEMM loop
        uint2 cmbp[4];
        #pragma unroll
        for (int j = 0; j < 4; j++)
            cmbp[j] = *(const uint2*)&combg[
                (((size_t)hg * 16 + (mbase >> 2) + quad) * 64 + j * 16 + l15) * 4];

        // B1: prev pass's attention/proj LDS reads done
        __syncthreads();
        // epilogue -> LDS. C/D layout: col = l15, row = quad*4 + r
        #pragma unroll
        for (int i = 0; i < 3; i++) {
            int f = wn * 3 + i, c = f >> 2, j = f & 3;
            int cw = j * 16 + l15;                 // 0..63 within pass
            float bias = b_qkv[c * 192 + p * 64 + cw];
            int hle = cw >> 5, d = cw & 31;
            if (c < 2) {
                unsigned short* dst = (c == 0) ? lq2 : lk2;
                #pragma unroll
                for (int mt = 0; mt < 2; mt++)
                    #pragma unroll
                    for (int r = 0; r < 4; r++) {
                        int t = wm * 32 + mt * 16 + quad * 4 + r;
                        dst[(hle * 64 + t) * 40 + d] = f2bf(acc[mt][i][r] + bias);
                    }
            } else {
                #pragma unroll
                for (int mt = 0; mt < 2; mt++) {
                    union { unsigned short s[4]; uint2 u; } pk;
                    #pragma unroll
                    for (int r = 0; r < 4; r++)
                        pk.s[r] = f2bf(acc[mt][i][r] + bias);
                    int t0 = wm * 32 + mt * 16 + quad * 4;
                    *(uint2*)&lvt2[(hle * 32 + d) * 72 + t0] = pk.u;
                }
            }
        }
        __syncthreads();   // B2: Q/K/V^T visible to all waves

        // ---- attention: 8 tasks, exactly one per wave ----
        // S = Q K^T (d=32 = one k-step)
        bf16x8 aq = *(const bf16x8*)&lq2[(hl * 64 + mbase + l15) * 40 + quad * 8];
        f32x4 sacc[4];
        #pragma unroll
        for (int j = 0; j < 4; j++) {
            bf16x8 bk = *(const bf16x8*)&lk2[(hl * 64 + j * 16 + l15) * 40 + quad * 8];
            f32x4 z = (f32x4){0.f, 0.f, 0.f, 0.f};
            sacc[j] = __builtin_amdgcn_mfma_f32_16x16x32_bf16(aq, bk, z, 0, 0, 0);
        }
        __syncthreads();   // B3: all lq2/lk2 reads done -> lsp overlay legal

        // softmax, per-row (P transient, stored unnormalized immediately)
        float rsum[4];
        #pragma unroll
        for (int r = 0; r < 4; r++) {
            float s0 = sacc[0][r] * SCALE + bfbits2f(((const unsigned short*)&cmbp[0])[r]);
            float s1 = sacc[1][r] * SCALE + bfbits2f(((const unsigned short*)&cmbp[1])[r]);
            float s2 = sacc[2][r] * SCALE + bfbits2f(((const unsigned short*)&cmbp[2])[r]);
            float s3 = sacc[3][r] * SCALE + bfbits2f(((const unsigned short*)&cmbp[3])[r]);
            float m = fmaxf(fmaxf(s0, s1), fmaxf(s2, s3));
            for (int o = 1; o < 16; o <<= 1) m = fmaxf(m, __shfl_xor(m, o, 64));
            float p0 = __expf(s0 - m), p1 = __expf(s1 - m);
            float p2 = __expf(s2 - m), p3 = __expf(s3 - m);
            float su = p0 + p1 + p2 + p3;
            for (int o = 1; o < 16; o <<= 1) su += __shfl_xor(su, o, 64);
            rsum[r] = su;
            int row = quad * 4 + r;
            lspw[row * 72 +  0 + l15] = f2bf(p0);
            lspw[row * 72 + 16 + l15] = f2bf(p1);
            lspw[row * 72 + 32 + l15] = f2bf(p2);
            lspw[row * 72 + 48 + l15] = f2bf(p3);
        }

        // O = P V^T  (K=64 -> 2 k-steps, 2 d-tiles); same-wave RAW on lspw
        f32x4 oacc[2];
        oacc[0] = (f32x4){0.f, 0.f, 0.f, 0.f};
        oacc[1] = (f32x4){0.f, 0.f, 0.f, 0.f};
        #pragma unroll
        for (int kstep = 0; kstep < 2; kstep++) {
            bf16x8 ap = *(const bf16x8*)&lspw[l15 * 72 + kstep * 32 + quad * 8];
            #pragma unroll
            for (int n2 = 0; n2 < 2; n2++) {
                bf16x8 bv = *(const bf16x8*)&lvt2[
                    (hl * 32 + n2 * 16 + l15) * 72 + kstep * 32 + quad * 8];
                oacc[n2] = __builtin_amdgcn_mfma_f32_16x16x32_bf16(ap, bv, oacc[n2], 0, 0, 0);
            }
        }

        // prefetch proj B-frags kk=0 (hide L2 latency under normalize + B4)
        bf16x8 pb0[3];
        #pragma unroll
        for (int nt = 0; nt < 3; nt++)
            pb0[nt] = *(const bf16x8*)&Wpf[
                ((size_t)((wn * 3 + nt) * 6 + (p * 2 + 0))) * 512 + lane * 8];

        // normalize + write Xa slice (bf16): col = hl*32 + d
        #pragma unroll
        for (int r = 0; r < 4; r++) {
            float inv = 1.0f / rsum[r];
            int t = mbase + quad * 4 + r;
            #pragma unroll
            for (int n2 = 0; n2 < 2; n2++)
                lxa[t * 72 + hl * 32 + n2 * 16 + l15] = f2bf(oacc[n2][r] * inv);
        }
        __syncthreads();   // B4: lxa visible cross-wave

        // ---- proj partial: rank-64 update, k-slice [p*64, p*64+64) ----
        bf16x8 pb1[3];
        #pragma unroll
        for (int nt = 0; nt < 3; nt++)
            pb1[nt] = *(const bf16x8*)&Wpf[
                ((size_t)((wn * 3 + nt) * 6 + (p * 2 + 1))) * 512 + lane * 8];
        bf16x8 pf[2][2];
        #pragma unroll
        for (int mt = 0; mt < 2; mt++)
            #pragma unroll
            for (int kk = 0; kk < 2; kk++)
                pf[mt][kk] = *(const bf16x8*)&lxa[
                    (wm * 32 + mt * 16 + l15) * 72 + kk * 32 + quad * 8];
        #pragma unroll
        for (int mt = 0; mt < 2; mt++)
            #pragma unroll
            for (int nt = 0; nt < 3; nt++)
                pacc[mt][nt] = __builtin_amdgcn_mfma_f32_16x16x32_bf16(
                    pf[mt][0], pb0[nt], pacc[mt][nt], 0, 0, 0);
        #pragma unroll
        for (int mt = 0; mt < 2; mt++)
            #pragma unroll
            for (int nt = 0; nt < 3; nt++)
                pacc[mt][nt] = __builtin_amdgcn_mfma_f32_16x16x32_bf16(
                    pf[mt][1], pb1[nt], pacc[mt][nt], 0, 0, 0);
        // next pass's B1 protects lq2/lk2/lvt2/lxa reuse
    }

    // ---- write out (fp32 + bias) ----
    for (int nt = 0; nt < 3; nt++) {
        int cw = wn * 48 + nt * 16 + l15;       // 0..191
        float bias = b_proj[cw];
        for (int mt = 0; mt < 2; mt++)
            for (int r = 0; r < 4; r++) {
                int t = wm * 32 + mt * 16 + quad * 4 + r;
                out[((size_t)bwin * 64 + t) * 192 + cw] = pacc[mt][nt][r] + bias;
            }
    }
}

// ---------------------------------------------------------------------------
extern "C" void kernel_launch(void* const* d_in, const int* in_sizes, int n_in,
                              void* d_out, int out_size, void* d_ws, size_t ws_size,
                              hipStream_t stream) {
    const float* x      = (const float*)d_in[0];
    const float* mask   = (const float*)d_in[1];
    const float* w_qkv  = (const float*)d_in[2];
    const float* b_qkv  = (const float*)d_in[3];
    const float* rpbt   = (const float*)d_in[4];
    const float* w_proj = (const float*)d_in[5];
    const float* b_proj = (const float*)d_in[6];
    float* out = (float*)d_out;

    const int B = in_sizes[0] / (NTOK * WDIM);   // 2048

    char* ws = (char*)d_ws;
    size_t o = 0;
    unsigned short* Wq = (unsigned short*)(ws + o); o += 576 * 192 * 2;
    unsigned short* Wp = (unsigned short*)(ws + o); o += 192 * 192 * 2;
    unsigned short* comb_bf = (unsigned short*)(ws + o);
    o += (size_t)64 * NH * NTOK * NTOK * 2;

    const int prep_elems = 576 * 192 + 192 * 192 + 64 * NH * NTOK * NTOK;
    prep_kernel<<<(prep_elems + 255) / 256, 256, 0, stream>>>(
        w_qkv, w_proj, rpbt, mask, Wq, Wp, comb_bf);
    fused_kernel<<<B, 512, 0, stream>>>(
        x, Wq, b_qkv, Wp, b_proj, comb_bf, out);
}

// Round 10
// 240.730 us; speedup vs baseline: 1.3898x; 1.0845x over previous
//
#include <hip/hip_runtime.h>
#include <hip/hip_bf16.h>
#include <cstdint>

// ---------------------------------------------------------------------------
// WindowAttention, fully fused: B windows (2048), N=64, DIM=192, H=6, d=32.
//   prep : weights -> bf16 MFMA-fragment-linear; comb = rel_bias+mask bf16
//          [w][h][q][key] row-major (lane's 4-key run = one 8B load)
//   fused: per-window block (512 thr, 8 waves). 3 passes over head-pairs:
//            QKV GEMM (A from persistent LDS X 2-deep, B from L2 2-deep,
//            BIAS PRE-LOADED INTO ACC) -> Q,K,V^T in LDS
//            -> attention with SWAPPED QK^T (S^T = mfma(K,Q)): each lane owns
//               one q-row's 16 keys -> softmax reduce = in-lane tree + 2
//               shuffles (was 32); P packed via plain bf16 casts (no inline
//               asm -- compiler emits the pack; m240: asm cvt_pk is slower);
//               PV swapped (O^T = mfma(V^T,P)) -> lane-local normalizer,
//               packed Xa stores
//            -> rank-64 proj update into reg acc (bias pre-loaded).
// R8 counters: VALUBusy 31.6 vs MfmaUtil 14.3 (VALU+serial-softmax bound);
// this round cuts ~100 VALU ops + 28 ds_swizzles per thread-pass.
// R9 failed opaquely (container x2, same signature as infra-flaky R2); only
// novel element -- inline-asm v_cvt_pk_bf16_f32 -- removed this round.
// Register budget: cap (512,4)=128 combined; peak (GEMM) ~116 unchanged.
// ---------------------------------------------------------------------------

#define NTOK 64
#define NH 6
#define HD 32
#define WDIM 192
#define SCALE 0.17677669529663689f

typedef __bf16 bf16x8 __attribute__((ext_vector_type(8)));
typedef float f32x4 __attribute__((ext_vector_type(4)));

__device__ inline unsigned short f2bf(float f) {
    union { __bf16 b; unsigned short s; } u;
    u.b = (__bf16)f;                     // native RNE convert
    return u.s;
}

__device__ inline float bfbits2f(unsigned short s) {
    union { unsigned u; float f; } v; v.u = ((unsigned)s) << 16;
    return v.f;
}

__device__ inline unsigned pack_bf16(float lo, float hi) {
    return (unsigned)f2bf(lo) | ((unsigned)f2bf(hi) << 16);
}

// ---------------------------------------------------------------------------
// K0: weight cast into MFMA B-fragment-linear order + combined bias table.
// Wfrag[((ntile*6 + ks)*64 + lane)*8 + j] = W[k][n], n = ntile*16+(lane&15),
// k = ks*32+(lane>>4)*8+j  -> a wave's B-fragment is one coalesced 1KB read.
// comb_bf[((w*6+h)*64 + q)*64 + k] = bf16(rpbt[relidx(q,k)][h] + mask[w][q][k])
// ---------------------------------------------------------------------------
__global__ __launch_bounds__(256) void prep_kernel(
    const float* __restrict__ w_qkv, const float* __restrict__ w_proj,
    const float* __restrict__ rpbt, const float* __restrict__ mask,
    unsigned short* __restrict__ wqkv_f, unsigned short* __restrict__ wproj_f,
    unsigned short* __restrict__ comb_bf) {
    int idx = blockIdx.x * 256 + threadIdx.x;
    if (idx < 576 * 192) {
        int j = idx & 7, lane = (idx >> 3) & 63, t = idx >> 9;   // t = 0..215
        int ks = t % 6, ntile = t / 6;                           // ntile 0..35
        int n = ntile * 16 + (lane & 15);                        // 0..575
        int k = ks * 32 + (lane >> 4) * 8 + j;                   // 0..191
        wqkv_f[idx] = f2bf(w_qkv[k * 576 + n]);
        return;
    }
    int i2 = idx - 576 * 192;
    if (i2 < 192 * 192) {
        int j = i2 & 7, lane = (i2 >> 3) & 63, t = i2 >> 9;      // t = 0..71
        int ks = t % 6, ntile = t / 6;                           // ntile 0..11
        int n = ntile * 16 + (lane & 15);                        // 0..191
        int k = ks * 32 + (lane >> 4) * 8 + j;                   // 0..191
        wproj_f[i2] = f2bf(w_proj[k * 192 + n]);
        return;
    }
    int i3 = i2 - 192 * 192;
    if (i3 < 64 * NH * NTOK * NTOK) {
        int k = i3 & 63;                     // key token
        int q = (i3 >> 6) & 63;              // query token
        int h = (i3 >> 12) % NH;
        int w = i3 / (NH * 4096);
        int rrd = (q >> 3) - (k >> 3) + 7;    // row-coord delta (0..14)
        int ccd = (q & 7) - (k & 7) + 7;      // col-coord delta (0..14)
        comb_bf[i3] = f2bf(rpbt[(rrd * 15 + ccd) * NH + h]
                           + mask[w * 4096 + q * 64 + k]);
    }
}

// ---------------------------------------------------------------------------
// Fused per-window kernel. 512 threads = 8 waves: wm = wave>>2 (row half),
// wn = wave&3 (n-group). Static LDS: sm[32256] shorts = 64512 B.
//   lx  : sm[0..12800)        X bf16 [64][200]  PERSISTENT (all passes)
//   lq2 : sm[12800..17920)    Q pair [2][64][40]
//   lk2 : sm[17920..23040)    K pair [2][64][40]
//   lvt2: sm[23040..27648)    V^T    [2][32][72]
//   lxa : sm[27648..32256)    Xa slice [64][72]
//   lsp : sm[12800 + wave*1152) P scratch [16][72]/wave, overlays lq2/lk2,
//         legalized by barrier B3 after the QK^T MFMA reads.
// Barriers/pass: B1 (pre-epilogue), B2 (post-epilogue), B3 (post-QK^T),
// B4 (pre-proj).
// ---------------------------------------------------------------------------
__global__ __launch_bounds__(512, 4) void fused_kernel(
    const float* __restrict__ X, const unsigned short* __restrict__ Wqf,
    const float* __restrict__ b_qkv, const unsigned short* __restrict__ Wpf,
    const float* __restrict__ b_proj, const unsigned short* __restrict__ comb_bf,
    float* __restrict__ out) {
    __shared__ unsigned short sm[32256];
    unsigned short* lx   = sm;              // [64][200] persistent
    unsigned short* lq2  = sm + 12800;      // [2][64][40]
    unsigned short* lk2  = sm + 17920;      // [2][64][40]
    unsigned short* lvt2 = sm + 23040;      // [2][32][72]
    unsigned short* lxa  = sm + 27648;      // [64][72]

    const int tid = threadIdx.x;
    const int bwin = blockIdx.x;
    const int wave = tid >> 6, lane = tid & 63;
    const int l15 = lane & 15, quad = lane >> 4;
    const int wm = wave >> 2, wn = wave & 3;

    unsigned short* lspw = sm + 12800 + wave * 1152;   // [16][72] per wave

    // ---- stage X (64x192 fp32 -> bf16) ----
    const float4* xg = (const float4*)(X + (size_t)bwin * 64 * 192);
    for (int i = 0; i < 6; i++) {
        int e4 = tid + i * 512;            // 3072 float4
        int row = e4 / 48, c4 = e4 % 48;
        float4 v = xg[e4];
        union { unsigned short s[4]; uint2 u; } pk;
        pk.s[0] = f2bf(v.x); pk.s[1] = f2bf(v.y);
        pk.s[2] = f2bf(v.z); pk.s[3] = f2bf(v.w);
        *(uint2*)&lx[row * 200 + c4 * 4] = pk.u;
    }
    __syncthreads();

    // proj accumulator, bias pre-loaded (out = pacc at the end, no add)
    f32x4 pacc[2][3];
    #pragma unroll
    for (int nt = 0; nt < 3; nt++) {
        float bp = b_proj[wn * 48 + nt * 16 + l15];
        pacc[0][nt] = (f32x4){bp, bp, bp, bp};
        pacc[1][nt] = (f32x4){bp, bp, bp, bp};
    }

    // per-(bwin&63) comb base, bf16 layout [w][h][q][key]
    const unsigned short* combg = comb_bf + ((size_t)(bwin & 63) * NH) * 4096;

    for (int p = 0; p < 3; p++) {
        const int hl = wm;                 // this wave's attn head (local)
        const int mbase = wn * 16;         // this wave's attn query tile
        const int hg = p * 2 + hl;         // global head

        // ---- QKV GEMM for head-pair p: A from LDS (2-deep), B from L2
        // (2-deep), bias pre-loaded into acc. Peak regs ~116 < 128 cap. ----
        const unsigned short* wptr[3];
        f32x4 acc[2][3];
        #pragma unroll
        for (int i = 0; i < 3; i++) {
            int f = wn * 3 + i, c = f >> 2, j = f & 3;
            wptr[i] = Wqf + ((size_t)((c * 12 + p * 4 + j) * 6)) * 512 + lane * 8;
            float bq = b_qkv[c * 192 + p * 64 + j * 16 + l15];
            acc[0][i] = (f32x4){bq, bq, bq, bq};
            acc[1][i] = (f32x4){bq, bq, bq, bq};
        }

        bf16x8 acur[2], anxt[2], bcur[3], bnxt[3];
        #pragma unroll
        for (int mt = 0; mt < 2; mt++)
            acur[mt] = *(const bf16x8*)&lx[(wm * 32 + mt * 16 + l15) * 200 + quad * 8];
        #pragma unroll
        for (int i = 0; i < 3; i++)
            bcur[i] = *(const bf16x8*)(wptr[i]);
        #pragma unroll
        for (int ks = 0; ks < 6; ks++) {
            if (ks < 5) {
                #pragma unroll
                for (int mt = 0; mt < 2; mt++)
                    anxt[mt] = *(const bf16x8*)&lx[
                        (wm * 32 + mt * 16 + l15) * 200 + (ks + 1) * 32 + quad * 8];
                #pragma unroll
                for (int i = 0; i < 3; i++)
                    bnxt[i] = *(const bf16x8*)(wptr[i] + (ks + 1) * 512);
            }
            #pragma unroll
            for (int mt = 0; mt < 2; mt++)
                #pragma unroll
                for (int i = 0; i < 3; i++)
                    acc[mt][i] = __builtin_amdgcn_mfma_f32_16x16x32_bf16(
                        acur[mt], bcur[i], acc[mt][i], 0, 0, 0);
            #pragma unroll
            for (int mt = 0; mt < 2; mt++) acur[mt] = anxt[mt];
            #pragma unroll
            for (int i = 0; i < 3; i++) bcur[i] = bnxt[i];
        }

        // packed comb loads (4 x 8B): q = mbase+l15, keys j*16+quad*4..+3;
        // latency hides under epilogue + B2 + QK^T
        uint2 cmbp[4];
        #pragma unroll
        for (int j = 0; j < 4; j++)
            cmbp[j] = *(const uint2*)&combg[
                ((size_t)hg * 64 + mbase + l15) * 64 + j * 16 + quad * 4];

        // B1: prev pass's attention/proj LDS reads done
        __syncthreads();
        // epilogue -> LDS (bias already in acc). C/D: col=l15, row=quad*4+r
        #pragma unroll
        for (int i = 0; i < 3; i++) {
            int f = wn * 3 + i, c = f >> 2, j = f & 3;
            int cw = j * 16 + l15;                 // 0..63 within pass
            int hle = cw >> 5, d = cw & 31;
            if (c < 2) {
                unsigned short* dst = (c == 0) ? lq2 : lk2;
                #pragma unroll
                for (int mt = 0; mt < 2; mt++)
                    #pragma unroll
                    for (int r = 0; r < 4; r++) {
                        int t = wm * 32 + mt * 16 + quad * 4 + r;
                        dst[(hle * 64 + t) * 40 + d] = f2bf(acc[mt][i][r]);
                    }
            } else {
                #pragma unroll
                for (int mt = 0; mt < 2; mt++) {
                    union { unsigned short s[4]; uint2 u; } pk;
                    #pragma unroll
                    for (int r = 0; r < 4; r++)
                        pk.s[r] = f2bf(acc[mt][i][r]);
                    int t0 = wm * 32 + mt * 16 + quad * 4;
                    *(uint2*)&lvt2[(hle * 32 + d) * 72 + t0] = pk.u;
                }
            }
        }
        __syncthreads();   // B2: Q/K/V^T visible to all waves

        // ---- attention, swapped: S^T = mfma(K, Q) ----
        // A-operand: K rows j*16+l15 (m-side); B-operand: Q row mbase+l15
        // (n-side). D: col(l15) = q-token, row(quad*4+r) = key j*16+quad*4+r
        // -> each lane owns q-row (mbase+l15) with 16 keys in-register.
        bf16x8 aq = *(const bf16x8*)&lq2[(hl * 64 + mbase + l15) * 40 + quad * 8];
        f32x4 sacc[4];
        #pragma unroll
        for (int j = 0; j < 4; j++) {
            bf16x8 bk = *(const bf16x8*)&lk2[(hl * 64 + j * 16 + l15) * 40 + quad * 8];
            f32x4 z = (f32x4){0.f, 0.f, 0.f, 0.f};
            sacc[j] = __builtin_amdgcn_mfma_f32_16x16x32_bf16(bk, aq, z, 0, 0, 0);
        }
        __syncthreads();   // B3: all lq2/lk2 reads done -> lsp overlay legal

        // softmax: 16 values in-lane; full row = same l15 across 4 quads
        // -> reduce = in-lane tree + shfl_xor(16) + shfl_xor(32)
        float s[4][4];
        #pragma unroll
        for (int j = 0; j < 4; j++) {
            unsigned lo = cmbp[j].x, hi = cmbp[j].y;
            s[j][0] = sacc[j][0] * SCALE + bfbits2f((unsigned short)lo);
            s[j][1] = sacc[j][1] * SCALE + bfbits2f((unsigned short)(lo >> 16));
            s[j][2] = sacc[j][2] * SCALE + bfbits2f((unsigned short)hi);
            s[j][3] = sacc[j][3] * SCALE + bfbits2f((unsigned short)(hi >> 16));
        }
        float m0 = fmaxf(fmaxf(s[0][0], s[0][1]), fmaxf(s[0][2], s[0][3]));
        float m1 = fmaxf(fmaxf(s[1][0], s[1][1]), fmaxf(s[1][2], s[1][3]));
        float m2 = fmaxf(fmaxf(s[2][0], s[2][1]), fmaxf(s[2][2], s[2][3]));
        float m3 = fmaxf(fmaxf(s[3][0], s[3][1]), fmaxf(s[3][2], s[3][3]));
        float m = fmaxf(fmaxf(m0, m1), fmaxf(m2, m3));
        m = fmaxf(m, __shfl_xor(m, 16, 64));
        m = fmaxf(m, __shfl_xor(m, 32, 64));
        float su = 0.f;
        #pragma unroll
        for (int j = 0; j < 4; j++)
            #pragma unroll
            for (int r = 0; r < 4; r++) {
                s[j][r] = __expf(s[j][r] - m);
                su += s[j][r];
            }
        su += __shfl_xor(su, 16, 64);
        su += __shfl_xor(su, 32, 64);

        // P (unnormalized, bf16-packed) -> wave P tile [q=l15][key],
        // keys j*16+quad*4+{0..3} as 2 dword stores per j
        #pragma unroll
        for (int j = 0; j < 4; j++) {
            unsigned d0 = pack_bf16(s[j][0], s[j][1]);
            unsigned d1 = pack_bf16(s[j][2], s[j][3]);
            *(unsigned*)&lspw[l15 * 72 + j * 16 + quad * 4]     = d0;
            *(unsigned*)&lspw[l15 * 72 + j * 16 + quad * 4 + 2] = d1;
        }

        // O^T = mfma(V^T, P): A = V^T rows (d), B = P rows (q-tokens).
        // D col(l15) = q-token, row = d within n2 tile. Same-wave RAW on lspw.
        f32x4 oacc[2];
        oacc[0] = (f32x4){0.f, 0.f, 0.f, 0.f};
        oacc[1] = (f32x4){0.f, 0.f, 0.f, 0.f};
        #pragma unroll
        for (int kstep = 0; kstep < 2; kstep++) {
            bf16x8 ap = *(const bf16x8*)&lspw[l15 * 72 + kstep * 32 + quad * 8];
            #pragma unroll
            for (int n2 = 0; n2 < 2; n2++) {
                bf16x8 bv = *(const bf16x8*)&lvt2[
                    (hl * 32 + n2 * 16 + l15) * 72 + kstep * 32 + quad * 8];
                oacc[n2] = __builtin_amdgcn_mfma_f32_16x16x32_bf16(bv, ap, oacc[n2], 0, 0, 0);
            }
        }

        // prefetch proj B-frags kk=0 (hide L2 latency under normalize + B4)
        bf16x8 pb0[3];
        #pragma unroll
        for (int nt = 0; nt < 3; nt++)
            pb0[nt] = *(const bf16x8*)&Wpf[
                ((size_t)((wn * 3 + nt) * 6 + (p * 2 + 0))) * 512 + lane * 8];

        // normalize (lane-local inv) + packed Xa store:
        // row t = mbase+l15, cols hl*32 + n2*16 + quad*4 + {0..3}
        float inv = 1.0f / su;
        #pragma unroll
        for (int n2 = 0; n2 < 2; n2++) {
            uint2 pk;
            pk.x = pack_bf16(oacc[n2][0] * inv, oacc[n2][1] * inv);
            pk.y = pack_bf16(oacc[n2][2] * inv, oacc[n2][3] * inv);
            *(uint2*)&lxa[(mbase + l15) * 72 + hl * 32 + n2 * 16 + quad * 4] = pk;
        }
        __syncthreads();   // B4: lxa visible cross-wave

        // ---- proj partial: rank-64 update, k-slice [p*64, p*64+64) ----
        bf16x8 pb1[3];
        #pragma unroll
        for (int nt = 0; nt < 3; nt++)
            pb1[nt] = *(const bf16x8*)&Wpf[
                ((size_t)((wn * 3 + nt) * 6 + (p * 2 + 1))) * 512 + lane * 8];
        bf16x8 pf[2][2];
        #pragma unroll
        for (int mt = 0; mt < 2; mt++)
            #pragma unroll
            for (int kk = 0; kk < 2; kk++)
                pf[mt][kk] = *(const bf16x8*)&lxa[
                    (wm * 32 + mt * 16 + l15) * 72 + kk * 32 + quad * 8];
        #pragma unroll
        for (int mt = 0; mt < 2; mt++)
            #pragma unroll
            for (int nt = 0; nt < 3; nt++)
                pacc[mt][nt] = __builtin_amdgcn_mfma_f32_16x16x32_bf16(
                    pf[mt][0], pb0[nt], pacc[mt][nt], 0, 0, 0);
        #pragma unroll
        for (int mt = 0; mt < 2; mt++)
            #pragma unroll
            for (int nt = 0; nt < 3; nt++)
                pacc[mt][nt] = __builtin_amdgcn_mfma_f32_16x16x32_bf16(
                    pf[mt][1], pb1[nt], pacc[mt][nt], 0, 0, 0);
        // next pass's B1 protects lq2/lk2/lvt2/lxa reuse
    }

    // ---- write out (fp32; bias already in pacc) ----
    for (int nt = 0; nt < 3; nt++) {
        int cw = wn * 48 + nt * 16 + l15;       // 0..191
        for (int mt = 0; mt < 2; mt++)
            for (int r = 0; r < 4; r++) {
                int t = wm * 32 + mt * 16 + quad * 4 + r;
                out[((size_t)bwin * 64 + t) * 192 + cw] = pacc[mt][nt][r];
            }
    }
}

// ---------------------------------------------------------------------------
extern "C" void kernel_launch(void* const* d_in, const int* in_sizes, int n_in,
                              void* d_out, int out_size, void* d_ws, size_t ws_size,
                              hipStream_t stream) {
    const float* x      = (const float*)d_in[0];
    const float* mask   = (const float*)d_in[1];
    const float* w_qkv  = (const float*)d_in[2];
    const float* b_qkv  = (const float*)d_in[3];
    const float* rpbt   = (const float*)d_in[4];
    const float* w_proj = (const float*)d_in[5];
    const float* b_proj = (const float*)d_in[6];
    float* out = (float*)d_out;

    const int B = in_sizes[0] / (NTOK * WDIM);   // 2048

    char* ws = (char*)d_ws;
    size_t o = 0;
    unsigned short* Wq = (unsigned short*)(ws + o); o += 576 * 192 * 2;
    unsigned short* Wp = (unsigned short*)(ws + o); o += 192 * 192 * 2;
    unsigned short* comb_bf = (unsigned short*)(ws + o);
    o += (size_t)64 * NH * NTOK * NTOK * 2;

    const int prep_elems = 576 * 192 + 192 * 192 + 64 * NH * NTOK * NTOK;
    prep_kernel<<<(prep_elems + 255) / 256, 256, 0, stream>>>(
        w_qkv, w_proj, rpbt, mask, Wq, Wp, comb_bf);
    fused_kernel<<<B, 512, 0, stream>>>(
        x, Wq, b_qkv, Wp, b_proj, comb_bf, out);
}